// Round 3
// baseline (638.230 us; speedup 1.0000x reference)
//
#include <hip/hip_runtime.h>
#include <hip/hip_bf16.h>

// RelativeAttention: out = ((softmax(((QK^T)*s + Q.rel)*s with mask) V) Wo + bo
// B=4 S=1024 D=1024 H=16 dk=64.  All matmuls in bf16 MFMA (16x16x32), f32 accum.

typedef unsigned short u16;
typedef unsigned int u32;
typedef __attribute__((ext_vector_type(8))) short bf16x8;
typedef __attribute__((ext_vector_type(4))) float f32x4;

#define SB 1024
#define DM 1024
#define NHD 16
#define DKH 64
#define NBATCH 4

// pin point: loads cannot be sunk past this; ALU not rescheduled across it
#define PIN() do { __builtin_amdgcn_sched_barrier(0); asm volatile("" ::: "memory"); } while (0)

__device__ __forceinline__ u16 f2bf(float x) {
  union { __hip_bfloat16 b; u16 u; } c;
  c.b = __float2bfloat16(x);
  return c.u;
}

__device__ __forceinline__ f32x4 mfma16(bf16x8 a, bf16x8 b, f32x4 c) {
  return __builtin_amdgcn_mfma_f32_16x16x32_bf16(a, b, c, 0, 0, 0);
}

__device__ __forceinline__ bf16x8 cvt8r(float4 v0, float4 v1) {
  bf16x8 r;
  r[0] = (short)f2bf(v0.x); r[1] = (short)f2bf(v0.y);
  r[2] = (short)f2bf(v0.z); r[3] = (short)f2bf(v0.w);
  r[4] = (short)f2bf(v1.x); r[5] = (short)f2bf(v1.y);
  r[6] = (short)f2bf(v1.z); r[7] = (short)f2bf(v1.w);
  return r;
}

// ---------------- f32 -> bf16 for the 3 input activations ----------------
__global__ void ra_convert_in(const float* __restrict__ q, const float* __restrict__ k,
                              const float* __restrict__ v,
                              u16* __restrict__ Xq, u16* __restrict__ Xk, u16* __restrict__ Xv)
{
  const int z = blockIdx.y;
  const float* src = (z == 0) ? q : (z == 1) ? k : v;
  u16* dst = (z == 0) ? Xq : (z == 1) ? Xk : Xv;
  const int n4 = NBATCH * SB * DM / 4;
  int idx = blockIdx.x * blockDim.x + threadIdx.x;
  int stride = gridDim.x * blockDim.x;
  for (int i = idx; i < n4; i += stride) {
    float4 v4 = *((const float4*)src + i);
    uint2 o;
    o.x = (u32)f2bf(v4.x) | ((u32)f2bf(v4.y) << 16);
    o.y = (u32)f2bf(v4.z) | ((u32)f2bf(v4.w) << 16);
    *((uint2*)dst + i) = o;
  }
}

// ---------------- W (f32 [k][n]) -> W^T (bf16 [n][k]) ----------------
__global__ void ra_transpose_w(const float* __restrict__ Wq, const float* __restrict__ Wk,
                               const float* __restrict__ Wv, const float* __restrict__ Wo,
                               u16* __restrict__ WqT, u16* __restrict__ WkT,
                               u16* __restrict__ WvT, u16* __restrict__ WoT)
{
  const int z = blockIdx.z;
  const float* W = (z == 0) ? Wq : (z == 1) ? Wk : (z == 2) ? Wv : Wo;
  u16* WT = (z == 0) ? WqT : (z == 1) ? WkT : (z == 2) ? WvT : WoT;
  __shared__ float tile[32][33];
  const int x0 = blockIdx.x * 32, y0 = blockIdx.y * 32;
  const int tx = threadIdx.x, ty = threadIdx.y;
#pragma unroll
  for (int yy = 0; yy < 4; ++yy) {
    int r = ty + yy * 8;
    tile[r][tx] = W[(size_t)(y0 + r) * DM + x0 + tx];
  }
  __syncthreads();
#pragma unroll
  for (int yy = 0; yy < 4; ++yy) {
    int r = ty + yy * 8;
    WT[(size_t)(x0 + r) * DM + y0 + tx] = f2bf(tile[tx][r]);
  }
}

// ---------------- shared 128x128x1024 bf16 GEMM core ----------------
__device__ __forceinline__ void gemm_core_128(const u16* __restrict__ A, const u16* __restrict__ Bt,
                                              int bm0, int bn0, u16* sh, f32x4 (&acc)[4][4])
{
  u16* As = sh;             // [128][72]
  u16* Bs = sh + 128 * 72;  // [128][72]
  const int tid = threadIdx.x;
  const int lane = tid & 63, wid = tid >> 6;
  const int l15 = lane & 15, l4 = lane >> 4;
  const int wr = (wid >> 1) * 64, wc = (wid & 1) * 64;
  for (int k0 = 0; k0 < DM; k0 += 64) {
#pragma unroll
    for (int it = 0; it < 4; ++it) {
      int c = tid + it * 256;
      int rw = c >> 3, kc = c & 7;
      *(uint4*)(As + rw * 72 + kc * 8) = *(const uint4*)(A + (size_t)(bm0 + rw) * DM + k0 + kc * 8);
      *(uint4*)(Bs + rw * 72 + kc * 8) = *(const uint4*)(Bt + (size_t)(bn0 + rw) * DM + k0 + kc * 8);
    }
    __syncthreads();
#pragma unroll
    for (int kf = 0; kf < 2; ++kf) {
      bf16x8 a[4], b[4];
#pragma unroll
      for (int mf = 0; mf < 4; ++mf)
        a[mf] = *(const bf16x8*)(As + (wr + mf * 16 + l15) * 72 + kf * 32 + l4 * 8);
#pragma unroll
      for (int nf = 0; nf < 4; ++nf)
        b[nf] = *(const bf16x8*)(Bs + (wc + nf * 16 + l15) * 72 + kf * 32 + l4 * 8);
#pragma unroll
      for (int mf = 0; mf < 4; ++mf)
#pragma unroll
        for (int nf = 0; nf < 4; ++nf)
          acc[mf][nf] = mfma16(a[mf], b[nf], acc[mf][nf]);
    }
    __syncthreads();
  }
}

// ---------------- projections: q/k -> [bh][s][dk], v -> [bh][dk][s] ----------------
__global__ __launch_bounds__(256, 2)
void ra_proj_gemm(const u16* __restrict__ Xq, const u16* __restrict__ Xk, const u16* __restrict__ Xv,
                  const u16* __restrict__ WqT, const u16* __restrict__ WkT, const u16* __restrict__ WvT,
                  const float* __restrict__ bq, const float* __restrict__ bk, const float* __restrict__ bv,
                  u16* __restrict__ q_ws, u16* __restrict__ k_ws, u16* __restrict__ vT_ws)
{
  __shared__ alignas(16) u16 sh[128 * 72 * 2];
  const int mode = blockIdx.z;
  const u16* A  = (mode == 0) ? Xq : (mode == 1) ? Xk : Xv;
  const u16* Bt = (mode == 0) ? WqT : (mode == 1) ? WkT : WvT;
  const float* bias = (mode == 0) ? bq : (mode == 1) ? bk : bv;
  const int bm0 = blockIdx.x * 128, bn0 = blockIdx.y * 128;
  f32x4 acc[4][4] = {};
  gemm_core_128(A, Bt, bm0, bn0, sh, acc);
  const int tid = threadIdx.x;
  const int lane = tid & 63, wid = tid >> 6;
  const int l15 = lane & 15, l4 = lane >> 4;
  const int wr = (wid >> 1) * 64, wc = (wid & 1) * 64;
  const int b_idx = bm0 >> 10;
  const int srow0 = bm0 & (SB - 1);
  if (mode < 2) {
    u16* outp = (mode == 0) ? q_ws : k_ws;
#pragma unroll
    for (int nf = 0; nf < 4; ++nf) {
      int nn = bn0 + wc + nf * 16 + l15;
      float bv_ = bias[nn];
      int h = nn >> 6, d = nn & 63;
#pragma unroll
      for (int mf = 0; mf < 4; ++mf)
#pragma unroll
        for (int r = 0; r < 4; ++r) {
          int m = wr + mf * 16 + l4 * 4 + r;
          outp[((size_t)(b_idx * NHD + h) * SB + srow0 + m) * DKH + d] = f2bf(acc[mf][nf][r] + bv_);
        }
    }
  } else {
    u16* ct = sh;  // [128][136]
#pragma unroll
    for (int nf = 0; nf < 4; ++nf) {
      int nl = wc + nf * 16 + l15;
      float bv_ = bias[bn0 + nl];
#pragma unroll
      for (int mf = 0; mf < 4; ++mf)
#pragma unroll
        for (int r = 0; r < 4; ++r) {
          int m = wr + mf * 16 + l4 * 4 + r;
          ct[nl * 136 + m] = f2bf(acc[mf][nf][r] + bv_);
        }
    }
    __syncthreads();
#pragma unroll
    for (int it = 0; it < 8; ++it) {
      int c = tid + it * 256;
      int n = c >> 4, mc2 = c & 15;
      uint4 v = *(const uint4*)(ct + n * 136 + mc2 * 8);
      int nn = bn0 + n;
      int h = nn >> 6, d = nn & 63;
      *(uint4*)(vT_ws + ((size_t)(b_idx * NHD + h) * DKH + d) * SB + srow0 + mc2 * 8) = v;
    }
  }
}

// ---------------- final projection: out = x @ Wo + bo (f32 out) ----------------
__global__ __launch_bounds__(256, 2)
void ra_out_gemm(const u16* __restrict__ X, const u16* __restrict__ WoT,
                 const float* __restrict__ bo, float* __restrict__ out)
{
  __shared__ alignas(16) u16 sh[128 * 72 * 2];
  const int bm0 = blockIdx.x * 128, bn0 = blockIdx.y * 128;
  f32x4 acc[4][4] = {};
  gemm_core_128(X, WoT, bm0, bn0, sh, acc);
  const int tid = threadIdx.x;
  const int lane = tid & 63, wid = tid >> 6;
  const int l15 = lane & 15, l4 = lane >> 4;
  const int wr = (wid >> 1) * 64, wc = (wid & 1) * 64;
#pragma unroll
  for (int nf = 0; nf < 4; ++nf) {
    int nn = bn0 + wc + nf * 16 + l15;
    float bv_ = bo[nn];
#pragma unroll
    for (int mf = 0; mf < 4; ++mf)
#pragma unroll
      for (int r = 0; r < 4; ++r) {
        int m = wr + mf * 16 + l4 * 4 + r;
        out[(size_t)(bm0 + m) * DM + nn] = acc[mf][nf][r] + bv_;
      }
  }
}

// ---------------- fused attention, v3 ----------------
// Block = (i-tile of 16, batch g), 8 waves.  Swapped-operand MFMAs put both
// score terms in softmax-ready layout: lane l15 = i, regs/l4 = j.
//   s1 = mfma(A=K_j_rows, B=Q_i_rows)         (per bh; wave owns bh = wid*2+bx)
//   s2 = mfma(A=Q_bh_rows, B=rel_j_rows)      (per i;  wave owns i  = wid*2+ix)
// s2 crosses waves through LDS (only cross-wave exchange -> 2 barriers/iter).
// All global loads are issue-pinned via sched_barrier+memory-clobber so the
// compiler cannot sink them to their uses; waits remain compiler-tracked.
__global__ __launch_bounds__(512, 2)
void ra_attn(const u16* __restrict__ q_ws, const u16* __restrict__ k_ws,
             const u16* __restrict__ vT_ws, const int* __restrict__ mask,
             const float* __restrict__ rel, u16* __restrict__ x_ws)
{
  __shared__ alignas(16) char smem[57344];
  float* s2t = (float*)smem;            // [256 rows = bh*16+i][36]
  u16*   p_t = (u16*)(smem + 36864);    // per-wave: [2*16 rows][40]

  const int tid = threadIdx.x, wid = tid >> 6, lane = tid & 63;
  const int l15 = lane & 15, l4 = lane >> 4;
  const int g = blockIdx.y, i0 = blockIdx.x * 16, bh0 = g * NHD;
  const float scl1 = 0.125f, scl2 = 0.015625f;  // 1/sqrt(dk), 1/dk
  u16* pw = p_t + wid * 1280;                   // wave-private p region

  // ---- persistent q fragments (loaded once) ----
  bf16x8 qs1[2][2];  // [bx][half]: B-frag for s1: q[bh, i=l15, d=l4*8+t]
  bf16x8 qs2[2][2];  // [ix][half]: A-frag for s2: q[bh=l15, i2, d=l4*8+t]
#pragma unroll
  for (int bx = 0; bx < 2; ++bx) {
    const u16* qp = q_ws + ((size_t)(bh0 + wid * 2 + bx) * SB + i0 + l15) * DKH + l4 * 8;
    qs1[bx][0] = *(const bf16x8*)qp;
    qs1[bx][1] = *(const bf16x8*)(qp + 32);
  }
#pragma unroll
  for (int ix = 0; ix < 2; ++ix) {
    const u16* qp = q_ws + ((size_t)(bh0 + l15) * SB + i0 + wid * 2 + ix) * DKH + l4 * 8;
    qs2[ix][0] = *(const bf16x8*)qp;
    qs2[ix][1] = *(const bf16x8*)(qp + 32);
  }

  // ---- loop-carried prefetch registers ----
  bf16x8 kr[2][2][2];   // [bx][nf][half]: K[bh, j=jb+nf*16+l15, d-half]
  float4 rr[2][2][4];   // [ix][nf][4]:    rel[i2, j=jb+nf*16+l15, d] f32

  // prologue: K(0), rel(0)
#pragma unroll
  for (int bx = 0; bx < 2; ++bx)
#pragma unroll
    for (int nf = 0; nf < 2; ++nf) {
      const u16* kp = k_ws + ((size_t)(bh0 + wid * 2 + bx) * SB + nf * 16 + l15) * DKH + l4 * 8;
      kr[bx][nf][0] = *(const bf16x8*)kp;
      kr[bx][nf][1] = *(const bf16x8*)(kp + 32);
    }
#pragma unroll
  for (int ix = 0; ix < 2; ++ix)
#pragma unroll
    for (int nf = 0; nf < 2; ++nf) {
      const float* rp = rel + ((size_t)(i0 + wid * 2 + ix) * SB + nf * 16 + l15) * DKH + l4 * 8;
      rr[ix][nf][0] = *(const float4*)rp;
      rr[ix][nf][1] = *(const float4*)(rp + 4);
      rr[ix][nf][2] = *(const float4*)(rp + 32);
      rr[ix][nf][3] = *(const float4*)(rp + 36);
    }
  PIN();

  f32x4 acc_o[2][4] = {};
  float m_run[2] = {-1e30f, -1e30f}, l_run[2] = {0.f, 0.f};

  for (int jt = 0; jt < 32; ++jt) {
    const int jb = jt * 32;
    const int jbn = (jt < 31) ? jb + 32 : 0;

    // ---- G1: issue V(jt) + mask(jt) ----
    bf16x8 vr[2][4];
#pragma unroll
    for (int bx = 0; bx < 2; ++bx)
#pragma unroll
      for (int df = 0; df < 4; ++df) {
        const u16* vp = vT_ws + ((size_t)(bh0 + wid * 2 + bx) * DKH + df * 16 + l15) * SB + jb + l4 * 8;
        vr[bx][df] = *(const bf16x8*)vp;
      }
    int4 mr[2];
#pragma unroll
    for (int nf = 0; nf < 2; ++nf)
      mr[nf] = *(const int4*)(mask + ((size_t)g * SB + i0 + l15) * SB + jb + nf * 16 + l4 * 4);
    PIN();

    // ---- A-s1: s1 = mfma(K, Q) -> regs (lane l15=i holds j = l4*4+r+16nf) ----
    f32x4 sc1[2][2];
#pragma unroll
    for (int bx = 0; bx < 2; ++bx)
#pragma unroll
      for (int nf = 0; nf < 2; ++nf) {
        f32x4 t = {};
        t = mfma16(kr[bx][nf][0], qs1[bx][0], t);
        t = mfma16(kr[bx][nf][1], qs1[bx][1], t);
        sc1[bx][nf] = t;
      }
    PIN();

    // ---- G2: reissue K for jt+1 ----
#pragma unroll
    for (int bx = 0; bx < 2; ++bx)
#pragma unroll
      for (int nf = 0; nf < 2; ++nf) {
        const u16* kp = k_ws + ((size_t)(bh0 + wid * 2 + bx) * SB + jbn + nf * 16 + l15) * DKH + l4 * 8;
        kr[bx][nf][0] = *(const bf16x8*)kp;
        kr[bx][nf][1] = *(const bf16x8*)(kp + 32);
      }
    PIN();

    // ---- A-s2: s2 = mfma(Q_bh, rel) -> LDS (rows bh*16+i, cols j) ----
#pragma unroll
    for (int ix = 0; ix < 2; ++ix) {
      const int i2 = wid * 2 + ix;
#pragma unroll
      for (int nf = 0; nf < 2; ++nf) {
        bf16x8 rb0 = cvt8r(rr[ix][nf][0], rr[ix][nf][1]);
        bf16x8 rb1 = cvt8r(rr[ix][nf][2], rr[ix][nf][3]);
        f32x4 t = {};
        t = mfma16(qs2[ix][0], rb0, t);
        t = mfma16(qs2[ix][1], rb1, t);
        // lane: value = s2[bh=l4*4+r][i2][j=nf*16+l15]
#pragma unroll
        for (int r = 0; r < 4; ++r)
          s2t[((l4 * 4 + r) * 16 + i2) * 36 + nf * 16 + l15] = t[r] * scl1;
      }
    }
    PIN();

    // ---- G3: reissue rel for jt+1 ----
#pragma unroll
    for (int ix = 0; ix < 2; ++ix)
#pragma unroll
      for (int nf = 0; nf < 2; ++nf) {
        const float* rp = rel + ((size_t)(i0 + wid * 2 + ix) * SB + jbn + nf * 16 + l15) * DKH + l4 * 8;
        rr[ix][nf][0] = *(const float4*)rp;
        rr[ix][nf][1] = *(const float4*)(rp + 4);
        rr[ix][nf][2] = *(const float4*)(rp + 32);
        rr[ix][nf][3] = *(const float4*)(rp + 36);
      }
    PIN();

    __syncthreads();  // s2 visible
    // ---- read s2 for own (bh, i=l15) rows ----
    f32x4 s2r[2][2];
#pragma unroll
    for (int bx = 0; bx < 2; ++bx) {
      const int row = (wid * 2 + bx) * 16 + l15;
#pragma unroll
      for (int nf = 0; nf < 2; ++nf)
        s2r[bx][nf] = *(const f32x4*)(s2t + row * 36 + nf * 16 + l4 * 4);
    }
    __syncthreads();  // reads done before next iter's writes

    // ---- softmax (per bx), fully in-register, p -> wave-private LDS ----
    float fscs[2];
#pragma unroll
    for (int bx = 0; bx < 2; ++bx) {
      float sv[8];
      float tmax = -3e38f;
#pragma unroll
      for (int nf = 0; nf < 2; ++nf) {
        int4 mm = mr[nf];
        float v0 = (mm.x == 0) ? -1e9f : sc1[bx][nf][0] * scl2 + s2r[bx][nf][0];
        float v1 = (mm.y == 0) ? -1e9f : sc1[bx][nf][1] * scl2 + s2r[bx][nf][1];
        float v2 = (mm.z == 0) ? -1e9f : sc1[bx][nf][2] * scl2 + s2r[bx][nf][2];
        float v3 = (mm.w == 0) ? -1e9f : sc1[bx][nf][3] * scl2 + s2r[bx][nf][3];
        sv[nf * 4 + 0] = v0; sv[nf * 4 + 1] = v1;
        sv[nf * 4 + 2] = v2; sv[nf * 4 + 3] = v3;
        tmax = fmaxf(tmax, fmaxf(fmaxf(v0, v1), fmaxf(v2, v3)));
      }
      tmax = fmaxf(tmax, __shfl_xor(tmax, 16));
      tmax = fmaxf(tmax, __shfl_xor(tmax, 32));
      const float m_new = fmaxf(m_run[bx], tmax);
      const float fsc = __expf(m_run[bx] - m_new);
      float p[8], psum = 0.f;
#pragma unroll
      for (int jj = 0; jj < 8; ++jj) {
        p[jj] = __expf(sv[jj] - m_new);
        psum += p[jj];
      }
      psum += __shfl_xor(psum, 16);
      psum += __shfl_xor(psum, 32);
      l_run[bx] = l_run[bx] * fsc + psum;
      m_run[bx] = m_new;
      fscs[bx] = fsc;
      // store p (bf16) at cols j = l4*4+16nf (+0..3), row bx*16+l15
#pragma unroll
      for (int nf = 0; nf < 2; ++nf) {
        uint2 w;
        w.x = (u32)f2bf(p[nf * 4 + 0]) | ((u32)f2bf(p[nf * 4 + 1]) << 16);
        w.y = (u32)f2bf(p[nf * 4 + 2]) | ((u32)f2bf(p[nf * 4 + 3]) << 16);
        *(uint2*)(pw + (bx * 16 + l15) * 40 + l4 * 4 + nf * 16) = w;
      }
    }

    // ---- PV: O = O*f + P.V  (wave-local p, f via shfl) ----
#pragma unroll
    for (int bx = 0; bx < 2; ++bx) {
      float f0 = __shfl(fscs[bx], l4 * 4 + 0);
      float f1 = __shfl(fscs[bx], l4 * 4 + 1);
      float f2 = __shfl(fscs[bx], l4 * 4 + 2);
      float f3 = __shfl(fscs[bx], l4 * 4 + 3);
      bf16x8 pa = *(const bf16x8*)(pw + (bx * 16 + l15) * 40 + l4 * 8);
#pragma unroll
      for (int df = 0; df < 4; ++df) {
        f32x4 c = acc_o[bx][df];
        c[0] *= f0; c[1] *= f1; c[2] *= f2; c[3] *= f3;
        acc_o[bx][df] = mfma16(pa, vr[bx][df], c);
      }
    }
  }

  // ---- epilogue: divide by softmax sum, write x[b][s][h*64+d] bf16 ----
#pragma unroll
  for (int bx = 0; bx < 2; ++bx) {
    float inv0 = 1.f / __shfl(l_run[bx], l4 * 4 + 0);
    float inv1 = 1.f / __shfl(l_run[bx], l4 * 4 + 1);
    float inv2 = 1.f / __shfl(l_run[bx], l4 * 4 + 2);
    float inv3 = 1.f / __shfl(l_run[bx], l4 * 4 + 3);
    const int col0 = (wid * 2 + bx) * DKH;
#pragma unroll
    for (int df = 0; df < 4; ++df) {
      x_ws[((size_t)g * SB + i0 + l4 * 4 + 0) * DM + col0 + df * 16 + l15] = f2bf(acc_o[bx][df][0] * inv0);
      x_ws[((size_t)g * SB + i0 + l4 * 4 + 1) * DM + col0 + df * 16 + l15] = f2bf(acc_o[bx][df][1] * inv1);
      x_ws[((size_t)g * SB + i0 + l4 * 4 + 2) * DM + col0 + df * 16 + l15] = f2bf(acc_o[bx][df][2] * inv2);
      x_ws[((size_t)g * SB + i0 + l4 * 4 + 3) * DM + col0 + df * 16 + l15] = f2bf(acc_o[bx][df][3] * inv3);
    }
  }
}

// ---------------- launch ----------------
extern "C" void kernel_launch(void* const* d_in, const int* in_sizes, int n_in,
                              void* d_out, int out_size, void* d_ws, size_t ws_size,
                              hipStream_t stream) {
  const float* query = (const float*)d_in[0];
  const float* key_  = (const float*)d_in[1];
  const float* value = (const float*)d_in[2];
  const int*   mask  = (const int*)d_in[3];
  const float* rel   = (const float*)d_in[4];
  const float* Wq = (const float*)d_in[5];
  const float* Wk = (const float*)d_in[6];
  const float* Wv = (const float*)d_in[7];
  const float* Wo = (const float*)d_in[8];
  const float* bq = (const float*)d_in[9];
  const float* bk = (const float*)d_in[10];
  const float* bv = (const float*)d_in[11];
  const float* bo = (const float*)d_in[12];
  float* out = (float*)d_out;
  char* ws = (char*)d_ws;

  u16* Xq   = (u16*)(ws + (0ull));
  u16* Xk   = (u16*)(ws + (8ull << 20));
  u16* Xv   = (u16*)(ws + (16ull << 20));
  u16* WqT  = (u16*)(ws + (24ull << 20));
  u16* WkT  = (u16*)(ws + (26ull << 20));
  u16* WvT  = (u16*)(ws + (28ull << 20));
  u16* WoT  = (u16*)(ws + (30ull << 20));
  u16* q_ws = (u16*)(ws + (32ull << 20));
  u16* k_ws = (u16*)(ws + (40ull << 20));
  u16* vT_ws= (u16*)(ws + (48ull << 20));
  u16* x_ws = (u16*)(ws + (56ull << 20));

  ra_convert_in<<<dim3(1024, 3), 256, 0, stream>>>(query, key_, value, Xq, Xk, Xv);
  ra_transpose_w<<<dim3(32, 32, 4), dim3(32, 8), 0, stream>>>(Wq, Wk, Wv, Wo, WqT, WkT, WvT, WoT);
  ra_proj_gemm<<<dim3(32, 8, 3), 256, 0, stream>>>(Xq, Xk, Xv, WqT, WkT, WvT, bq, bk, bv,
                                                   q_ws, k_ws, vT_ws);
  ra_attn<<<dim3(64, 4), 512, 0, stream>>>(q_ws, k_ws, vT_ws, mask, rel, x_ws);
  ra_out_gemm<<<dim3(32, 8), 256, 0, stream>>>(x_ws, WoT, bo, out);
}

// Round 4
// 466.353 us; speedup vs baseline: 1.3686x; 1.3686x over previous
//
#include <hip/hip_runtime.h>
#include <hip/hip_bf16.h>

// RelativeAttention: out = ((softmax(((QK^T)*s + Q.rel)*s with mask) V) Wo + bo
// B=4 S=1024 D=1024 H=16 dk=64.  All matmuls in bf16 MFMA (16x16x32), f32 accum.

typedef unsigned short u16;
typedef unsigned int u32;
typedef __attribute__((ext_vector_type(8))) short bf16x8;
typedef __attribute__((ext_vector_type(4))) float f32x4;
typedef __attribute__((ext_vector_type(8))) _Float16 f16x8;

#define SB 1024
#define DM 1024
#define NHD 16
#define DKH 64
#define NBATCH 4

// pin point: loads above cannot sink below; loads below cannot hoist above
#define PIN() do { __builtin_amdgcn_sched_barrier(0); asm volatile("" ::: "memory"); } while (0)

__device__ __forceinline__ u16 f2bf(float x) {
  union { __hip_bfloat16 b; u16 u; } c;
  c.b = __float2bfloat16(x);
  return c.u;
}

__device__ __forceinline__ f32x4 mfma16(bf16x8 a, bf16x8 b, f32x4 c) {
  return __builtin_amdgcn_mfma_f32_16x16x32_bf16(a, b, c, 0, 0, 0);
}

__device__ __forceinline__ bf16x8 cvt8r(float4 v0, float4 v1) {
  bf16x8 r;
  r[0] = (short)f2bf(v0.x); r[1] = (short)f2bf(v0.y);
  r[2] = (short)f2bf(v0.z); r[3] = (short)f2bf(v0.w);
  r[4] = (short)f2bf(v1.x); r[5] = (short)f2bf(v1.y);
  r[6] = (short)f2bf(v1.z); r[7] = (short)f2bf(v1.w);
  return r;
}

// ---------------- f32 -> bf16 for the 3 input activations ----------------
__global__ void ra_convert_in(const float* __restrict__ q, const float* __restrict__ k,
                              const float* __restrict__ v,
                              u16* __restrict__ Xq, u16* __restrict__ Xk, u16* __restrict__ Xv)
{
  const int z = blockIdx.y;
  const float* src = (z == 0) ? q : (z == 1) ? k : v;
  u16* dst = (z == 0) ? Xq : (z == 1) ? Xk : Xv;
  const int n4 = NBATCH * SB * DM / 4;
  int idx = blockIdx.x * blockDim.x + threadIdx.x;
  int stride = gridDim.x * blockDim.x;
  for (int i = idx; i < n4; i += stride) {
    float4 v4 = *((const float4*)src + i);
    uint2 o;
    o.x = (u32)f2bf(v4.x) | ((u32)f2bf(v4.y) << 16);
    o.y = (u32)f2bf(v4.z) | ((u32)f2bf(v4.w) << 16);
    *((uint2*)dst + i) = o;
  }
}

// ---------------- W (f32 [k][n]) -> W^T (bf16 [n][k]) ----------------
__global__ void ra_transpose_w(const float* __restrict__ Wq, const float* __restrict__ Wk,
                               const float* __restrict__ Wv, const float* __restrict__ Wo,
                               u16* __restrict__ WqT, u16* __restrict__ WkT,
                               u16* __restrict__ WvT, u16* __restrict__ WoT)
{
  const int z = blockIdx.z;
  const float* W = (z == 0) ? Wq : (z == 1) ? Wk : (z == 2) ? Wv : Wo;
  u16* WT = (z == 0) ? WqT : (z == 1) ? WkT : (z == 2) ? WvT : WoT;
  __shared__ float tile[32][33];
  const int x0 = blockIdx.x * 32, y0 = blockIdx.y * 32;
  const int tx = threadIdx.x, ty = threadIdx.y;
#pragma unroll
  for (int yy = 0; yy < 4; ++yy) {
    int r = ty + yy * 8;
    tile[r][tx] = W[(size_t)(y0 + r) * DM + x0 + tx];
  }
  __syncthreads();
#pragma unroll
  for (int yy = 0; yy < 4; ++yy) {
    int r = ty + yy * 8;
    WT[(size_t)(x0 + r) * DM + y0 + tx] = f2bf(tile[tx][r]);
  }
}

// ---------------- shared 128x128x1024 bf16 GEMM core ----------------
__device__ __forceinline__ void gemm_core_128(const u16* __restrict__ A, const u16* __restrict__ Bt,
                                              int bm0, int bn0, u16* sh, f32x4 (&acc)[4][4])
{
  u16* As = sh;             // [128][72]
  u16* Bs = sh + 128 * 72;  // [128][72]
  const int tid = threadIdx.x;
  const int lane = tid & 63, wid = tid >> 6;
  const int l15 = lane & 15, l4 = lane >> 4;
  const int wr = (wid >> 1) * 64, wc = (wid & 1) * 64;
  for (int k0 = 0; k0 < DM; k0 += 64) {
#pragma unroll
    for (int it = 0; it < 4; ++it) {
      int c = tid + it * 256;
      int rw = c >> 3, kc = c & 7;
      *(uint4*)(As + rw * 72 + kc * 8) = *(const uint4*)(A + (size_t)(bm0 + rw) * DM + k0 + kc * 8);
      *(uint4*)(Bs + rw * 72 + kc * 8) = *(const uint4*)(Bt + (size_t)(bn0 + rw) * DM + k0 + kc * 8);
    }
    __syncthreads();
#pragma unroll
    for (int kf = 0; kf < 2; ++kf) {
      bf16x8 a[4], b[4];
#pragma unroll
      for (int mf = 0; mf < 4; ++mf)
        a[mf] = *(const bf16x8*)(As + (wr + mf * 16 + l15) * 72 + kf * 32 + l4 * 8);
#pragma unroll
      for (int nf = 0; nf < 4; ++nf)
        b[nf] = *(const bf16x8*)(Bs + (wc + nf * 16 + l15) * 72 + kf * 32 + l4 * 8);
#pragma unroll
      for (int mf = 0; mf < 4; ++mf)
#pragma unroll
        for (int nf = 0; nf < 4; ++nf)
          acc[mf][nf] = mfma16(a[mf], b[nf], acc[mf][nf]);
    }
    __syncthreads();
  }
}

// ---------------- projections: q/k -> [bh][s][dk], v -> [bh][dk][s] ----------------
__global__ __launch_bounds__(256, 2)
void ra_proj_gemm(const u16* __restrict__ Xq, const u16* __restrict__ Xk, const u16* __restrict__ Xv,
                  const u16* __restrict__ WqT, const u16* __restrict__ WkT, const u16* __restrict__ WvT,
                  const float* __restrict__ bq, const float* __restrict__ bk, const float* __restrict__ bv,
                  u16* __restrict__ q_ws, u16* __restrict__ k_ws, u16* __restrict__ vT_ws)
{
  __shared__ alignas(16) u16 sh[128 * 72 * 2];
  const int mode = blockIdx.z;
  const u16* A  = (mode == 0) ? Xq : (mode == 1) ? Xk : Xv;
  const u16* Bt = (mode == 0) ? WqT : (mode == 1) ? WkT : WvT;
  const float* bias = (mode == 0) ? bq : (mode == 1) ? bk : bv;
  const int bm0 = blockIdx.x * 128, bn0 = blockIdx.y * 128;
  f32x4 acc[4][4] = {};
  gemm_core_128(A, Bt, bm0, bn0, sh, acc);
  const int tid = threadIdx.x;
  const int lane = tid & 63, wid = tid >> 6;
  const int l15 = lane & 15, l4 = lane >> 4;
  const int wr = (wid >> 1) * 64, wc = (wid & 1) * 64;
  const int b_idx = bm0 >> 10;
  const int srow0 = bm0 & (SB - 1);
  if (mode < 2) {
    u16* outp = (mode == 0) ? q_ws : k_ws;
#pragma unroll
    for (int nf = 0; nf < 4; ++nf) {
      int nn = bn0 + wc + nf * 16 + l15;
      float bv_ = bias[nn];
      int h = nn >> 6, d = nn & 63;
#pragma unroll
      for (int mf = 0; mf < 4; ++mf)
#pragma unroll
        for (int r = 0; r < 4; ++r) {
          int m = wr + mf * 16 + l4 * 4 + r;
          outp[((size_t)(b_idx * NHD + h) * SB + srow0 + m) * DKH + d] = f2bf(acc[mf][nf][r] + bv_);
        }
    }
  } else {
    u16* ct = sh;  // [128][136]
#pragma unroll
    for (int nf = 0; nf < 4; ++nf) {
      int nl = wc + nf * 16 + l15;
      float bv_ = bias[bn0 + nl];
#pragma unroll
      for (int mf = 0; mf < 4; ++mf)
#pragma unroll
        for (int r = 0; r < 4; ++r) {
          int m = wr + mf * 16 + l4 * 4 + r;
          ct[nl * 136 + m] = f2bf(acc[mf][nf][r] + bv_);
        }
    }
    __syncthreads();
#pragma unroll
    for (int it = 0; it < 8; ++it) {
      int c = tid + it * 256;
      int n = c >> 4, mc2 = c & 15;
      uint4 v = *(const uint4*)(ct + n * 136 + mc2 * 8);
      int nn = bn0 + n;
      int h = nn >> 6, d = nn & 63;
      *(uint4*)(vT_ws + ((size_t)(b_idx * NHD + h) * DKH + d) * SB + srow0 + mc2 * 8) = v;
    }
  }
}

// ---------------- final projection: out = x @ Wo + bo (f32 out) ----------------
__global__ __launch_bounds__(256, 2)
void ra_out_gemm(const u16* __restrict__ X, const u16* __restrict__ WoT,
                 const float* __restrict__ bo, float* __restrict__ out)
{
  __shared__ alignas(16) u16 sh[128 * 72 * 2];
  const int bm0 = blockIdx.x * 128, bn0 = blockIdx.y * 128;
  f32x4 acc[4][4] = {};
  gemm_core_128(X, WoT, bm0, bn0, sh, acc);
  const int tid = threadIdx.x;
  const int lane = tid & 63, wid = tid >> 6;
  const int l15 = lane & 15, l4 = lane >> 4;
  const int wr = (wid >> 1) * 64, wc = (wid & 1) * 64;
#pragma unroll
  for (int nf = 0; nf < 4; ++nf) {
    int nn = bn0 + wc + nf * 16 + l15;
    float bv_ = bo[nn];
#pragma unroll
    for (int mf = 0; mf < 4; ++mf)
#pragma unroll
      for (int r = 0; r < 4; ++r) {
        int m = wr + mf * 16 + l4 * 4 + r;
        out[(size_t)(bm0 + m) * DM + nn] = acc[mf][nf][r] + bv_;
      }
  }
}

// ---------------- fused attention, v4: j-split 2-way + batched pinned loads ----------------
// Block = (i-tile 16, batch g, j-half). 8 waves, 512 blocks -> 2 independent blocks/CU.
// Swapped MFMAs keep softmax per-lane (lane l15 = i, regs = j). s2 (bh<->i transpose)
// exchanged via LDS with 2 barriers. Per-iteration load batches sized <=88 VGPRs and
// consumed promptly (no cross-iteration prefetch) so nothing spills at the 128 cap.
// Output: normalized partial O (fp16) + per-row (m,l) for the combine kernel.
__global__ __launch_bounds__(512, 4)
void ra_attn(const u16* __restrict__ q_ws, const u16* __restrict__ k_ws,
             const u16* __restrict__ vT_ws, const int* __restrict__ mask,
             const float* __restrict__ rel, _Float16* __restrict__ o_part,
             float2* __restrict__ ml)
{
  __shared__ alignas(16) char smem[57344];
  float* s2t = (float*)smem;            // [256 rows = bh*16+i][36] f32
  u16*   p_t = (u16*)(smem + 36864);    // [256 rows][40] u16 (wave-disjoint rows)

  const int tid = threadIdx.x, wid = tid >> 6, lane = tid & 63;
  const int l15 = lane & 15, l4 = lane >> 4;
  const int g = blockIdx.y, i0 = blockIdx.x * 16, bh0 = g * NHD;
  const int js = blockIdx.z, j0 = js * 512;
  const float scl1 = 0.125f, scl2 = 0.015625f;  // 1/sqrt(dk), 1/dk

  f32x4 acc_o[2][4] = {};
  float m_run[2] = {-1e30f, -1e30f}, l_run[2] = {0.f, 0.f};

  for (int jt = 0; jt < 16; ++jt) {
    const int jb = j0 + jt * 32;

    // ---- G1: rel(f32, both ix) + q2(both ix)  [~80 VGPRs, consumed below] ----
    float4 rr[2][2][4];
    bf16x8 q2[2][2];
#pragma unroll
    for (int ix = 0; ix < 2; ++ix) {
      const int i2 = wid * 2 + ix;
#pragma unroll
      for (int nf = 0; nf < 2; ++nf) {
        const float* rp = rel + ((size_t)(i0 + i2) * SB + jb + nf * 16 + l15) * DKH + l4 * 8;
        rr[ix][nf][0] = *(const float4*)rp;
        rr[ix][nf][1] = *(const float4*)(rp + 4);
        rr[ix][nf][2] = *(const float4*)(rp + 32);
        rr[ix][nf][3] = *(const float4*)(rp + 36);
      }
      const u16* qp = q_ws + ((size_t)(bh0 + l15) * SB + i0 + i2) * DKH + l4 * 8;
      q2[ix][0] = *(const bf16x8*)qp;
      q2[ix][1] = *(const bf16x8*)(qp + 32);
    }
    PIN();

    // ---- s2 = mfma(Q_bh, rel) -> LDS rows (bh*16+i), cols j ----
#pragma unroll
    for (int ix = 0; ix < 2; ++ix) {
      const int i2 = wid * 2 + ix;
#pragma unroll
      for (int nf = 0; nf < 2; ++nf) {
        bf16x8 rb0 = cvt8r(rr[ix][nf][0], rr[ix][nf][1]);
        bf16x8 rb1 = cvt8r(rr[ix][nf][2], rr[ix][nf][3]);
        f32x4 t = {};
        t = mfma16(q2[ix][0], rb0, t);
        t = mfma16(q2[ix][1], rb1, t);
#pragma unroll
        for (int r = 0; r < 4; ++r)
          s2t[((l4 * 4 + r) * 16 + i2) * 36 + nf * 16 + l15] = t[r] * scl1;
      }
    }
    PIN();

    // ---- G3: K + q1 + mask  [56 VGPRs; latency hides under barriers/s2 exchange] ----
    bf16x8 kr[2][2][2], q1[2][2];
    int4 mr[2];
#pragma unroll
    for (int bx = 0; bx < 2; ++bx) {
      const int bh = bh0 + wid * 2 + bx;
#pragma unroll
      for (int nf = 0; nf < 2; ++nf) {
        const u16* kp = k_ws + ((size_t)bh * SB + jb + nf * 16 + l15) * DKH + l4 * 8;
        kr[bx][nf][0] = *(const bf16x8*)kp;
        kr[bx][nf][1] = *(const bf16x8*)(kp + 32);
      }
      const u16* qp = q_ws + ((size_t)bh * SB + i0 + l15) * DKH + l4 * 8;
      q1[bx][0] = *(const bf16x8*)qp;
      q1[bx][1] = *(const bf16x8*)(qp + 32);
    }
#pragma unroll
    for (int nf = 0; nf < 2; ++nf)
      mr[nf] = *(const int4*)(mask + ((size_t)g * SB + i0 + l15) * SB + jb + nf * 16 + l4 * 4);
    PIN();

    __syncthreads();  // s2 writes visible
    f32x4 s2r[2][2];
#pragma unroll
    for (int bx = 0; bx < 2; ++bx) {
      const int row = (wid * 2 + bx) * 16 + l15;
#pragma unroll
      for (int nf = 0; nf < 2; ++nf)
        s2r[bx][nf] = *(const f32x4*)(s2t + row * 36 + nf * 16 + l4 * 4);
    }
    __syncthreads();  // reads done before next iteration's writes

    // ---- s1 = mfma(K, Q): lane l15 = i, holds j = jb + nf*16 + l4*4 + r ----
    f32x4 sc1[2][2];
#pragma unroll
    for (int bx = 0; bx < 2; ++bx)
#pragma unroll
      for (int nf = 0; nf < 2; ++nf) {
        f32x4 t = {};
        t = mfma16(kr[bx][nf][0], q1[bx][0], t);
        t = mfma16(kr[bx][nf][1], q1[bx][1], t);
        sc1[bx][nf] = t;
      }

    // ---- G4: V  [32 VGPRs; hides under softmax] ----
    bf16x8 vr[2][4];
#pragma unroll
    for (int bx = 0; bx < 2; ++bx)
#pragma unroll
      for (int df = 0; df < 4; ++df) {
        const u16* vp = vT_ws + ((size_t)(bh0 + wid * 2 + bx) * DKH + df * 16 + l15) * SB + jb + l4 * 8;
        vr[bx][df] = *(const bf16x8*)vp;
      }
    PIN();

    // ---- softmax per bx, in-register; p -> wave-owned p_t rows ----
    float fscs[2];
#pragma unroll
    for (int bx = 0; bx < 2; ++bx) {
      float sv[8];
      float tmax = -3e38f;
#pragma unroll
      for (int nf = 0; nf < 2; ++nf) {
        int4 mm = mr[nf];
        float v0 = (mm.x == 0) ? -1e9f : sc1[bx][nf][0] * scl2 + s2r[bx][nf][0];
        float v1 = (mm.y == 0) ? -1e9f : sc1[bx][nf][1] * scl2 + s2r[bx][nf][1];
        float v2 = (mm.z == 0) ? -1e9f : sc1[bx][nf][2] * scl2 + s2r[bx][nf][2];
        float v3 = (mm.w == 0) ? -1e9f : sc1[bx][nf][3] * scl2 + s2r[bx][nf][3];
        sv[nf * 4 + 0] = v0; sv[nf * 4 + 1] = v1;
        sv[nf * 4 + 2] = v2; sv[nf * 4 + 3] = v3;
        tmax = fmaxf(tmax, fmaxf(fmaxf(v0, v1), fmaxf(v2, v3)));
      }
      tmax = fmaxf(tmax, __shfl_xor(tmax, 16));
      tmax = fmaxf(tmax, __shfl_xor(tmax, 32));
      const float m_new = fmaxf(m_run[bx], tmax);
      const float fsc = __expf(m_run[bx] - m_new);
      float p[8], psum = 0.f;
#pragma unroll
      for (int jj = 0; jj < 8; ++jj) {
        p[jj] = __expf(sv[jj] - m_new);
        psum += p[jj];
      }
      psum += __shfl_xor(psum, 16);
      psum += __shfl_xor(psum, 32);
      l_run[bx] = l_run[bx] * fsc + psum;
      m_run[bx] = m_new;
      fscs[bx] = fsc;
      const int row = (wid * 2 + bx) * 16 + l15;
#pragma unroll
      for (int nf = 0; nf < 2; ++nf) {
        uint2 w;
        w.x = (u32)f2bf(p[nf * 4 + 0]) | ((u32)f2bf(p[nf * 4 + 1]) << 16);
        w.y = (u32)f2bf(p[nf * 4 + 2]) | ((u32)f2bf(p[nf * 4 + 3]) << 16);
        *(uint2*)(p_t + row * 40 + l4 * 4 + nf * 16) = w;
      }
    }

    // ---- PV: O = O*f + P.V (wave-local p rows; f via shfl) ----
#pragma unroll
    for (int bx = 0; bx < 2; ++bx) {
      float f0 = __shfl(fscs[bx], l4 * 4 + 0);
      float f1 = __shfl(fscs[bx], l4 * 4 + 1);
      float f2 = __shfl(fscs[bx], l4 * 4 + 2);
      float f3 = __shfl(fscs[bx], l4 * 4 + 3);
      const int row = (wid * 2 + bx) * 16 + l15;
      bf16x8 pa = *(const bf16x8*)(p_t + row * 40 + l4 * 8);
#pragma unroll
      for (int df = 0; df < 4; ++df) {
        f32x4 c = acc_o[bx][df];
        c[0] *= f0; c[1] *= f1; c[2] *= f2; c[3] *= f3;
        acc_o[bx][df] = mfma16(pa, vr[bx][df], c);
      }
    }
  }

  // ---- epilogue: normalized partial O (fp16) + (m,l) per row ----
#pragma unroll
  for (int bx = 0; bx < 2; ++bx) {
    const int bh = wid * 2 + bx;
    float l0 = __shfl(l_run[bx], l4 * 4 + 0);
    float l1 = __shfl(l_run[bx], l4 * 4 + 1);
    float l2 = __shfl(l_run[bx], l4 * 4 + 2);
    float l3 = __shfl(l_run[bx], l4 * 4 + 3);
    float inv0 = (l0 > 0.f) ? 1.f / l0 : 0.f;
    float inv1 = (l1 > 0.f) ? 1.f / l1 : 0.f;
    float inv2 = (l2 > 0.f) ? 1.f / l2 : 0.f;
    float inv3 = (l3 > 0.f) ? 1.f / l3 : 0.f;
    const size_t base = ((size_t)(js * NBATCH + g) * SB) * DM;
#pragma unroll
    for (int df = 0; df < 4; ++df) {
      const int col = bh * DKH + df * 16 + l15;
      o_part[base + (size_t)(i0 + l4 * 4 + 0) * DM + col] = (_Float16)(acc_o[bx][df][0] * inv0);
      o_part[base + (size_t)(i0 + l4 * 4 + 1) * DM + col] = (_Float16)(acc_o[bx][df][1] * inv1);
      o_part[base + (size_t)(i0 + l4 * 4 + 2) * DM + col] = (_Float16)(acc_o[bx][df][2] * inv2);
      o_part[base + (size_t)(i0 + l4 * 4 + 3) * DM + col] = (_Float16)(acc_o[bx][df][3] * inv3);
    }
    if (l4 == 0) {
      // lane l15 holds row i0+l15's (m,l)
      ml[((size_t)(js * NBATCH + g) * NHD + bh) * SB + i0 + l15] =
          make_float2(m_run[bx], l_run[bx]);
    }
  }
}

// ---------------- combine the two j-split halves ----------------
__global__ __launch_bounds__(256)
void ra_combine(const _Float16* __restrict__ o_part, const float2* __restrict__ ml,
                u16* __restrict__ x_ws)
{
  const int t = blockIdx.x * 256 + threadIdx.x;   // 524288 threads = rows*8
  const int row = t >> 3, dbase = (t & 7) * 8;
  const int g = row >> 14, s = (row >> 4) & 1023, h = row & 15;
  const float2 a = ml[((size_t)(0 * NBATCH + g) * NHD + h) * SB + s];
  const float2 b = ml[((size_t)(1 * NBATCH + g) * NHD + h) * SB + s];
  const float M = fmaxf(a.x, b.x);
  const float w1 = a.y * __expf(a.x - M);
  const float w2 = b.y * __expf(b.x - M);
  const float ws = w1 + w2;
  const float inv = (ws > 0.f) ? 1.f / ws : 0.f;
  const size_t off1 = ((size_t)g * SB + s) * DM + h * DKH + dbase;
  const size_t off2 = off1 + (size_t)NBATCH * SB * DM;
  f16x8 v1 = *(const f16x8*)(o_part + off1);
  f16x8 v2 = *(const f16x8*)(o_part + off2);
#pragma unroll
  for (int d = 0; d < 8; ++d)
    x_ws[off1 + d] = f2bf((w1 * (float)v1[d] + w2 * (float)v2[d]) * inv);
}

// ---------------- launch ----------------
extern "C" void kernel_launch(void* const* d_in, const int* in_sizes, int n_in,
                              void* d_out, int out_size, void* d_ws, size_t ws_size,
                              hipStream_t stream) {
  const float* query = (const float*)d_in[0];
  const float* key_  = (const float*)d_in[1];
  const float* value = (const float*)d_in[2];
  const int*   mask  = (const int*)d_in[3];
  const float* rel   = (const float*)d_in[4];
  const float* Wq = (const float*)d_in[5];
  const float* Wk = (const float*)d_in[6];
  const float* Wv = (const float*)d_in[7];
  const float* Wo = (const float*)d_in[8];
  const float* bq = (const float*)d_in[9];
  const float* bk = (const float*)d_in[10];
  const float* bv = (const float*)d_in[11];
  const float* bo = (const float*)d_in[12];
  float* out = (float*)d_out;
  char* ws = (char*)d_ws;

  // workspace layout (64 MB):
  //  [0,16)   o_part (fp16, 2 j-splits)   -- overlays Xq/Xk (dead after proj)
  //  [16,17)  ml (float2 per row, 2 splits) -- overlays Xv head (dead after proj)
  u16* Xq   = (u16*)(ws + (0ull));
  u16* Xk   = (u16*)(ws + (8ull << 20));
  u16* Xv   = (u16*)(ws + (16ull << 20));
  u16* WqT  = (u16*)(ws + (24ull << 20));
  u16* WkT  = (u16*)(ws + (26ull << 20));
  u16* WvT  = (u16*)(ws + (28ull << 20));
  u16* WoT  = (u16*)(ws + (30ull << 20));
  u16* q_ws = (u16*)(ws + (32ull << 20));
  u16* k_ws = (u16*)(ws + (40ull << 20));
  u16* vT_ws= (u16*)(ws + (48ull << 20));
  u16* x_ws = (u16*)(ws + (56ull << 20));
  _Float16* o_part = (_Float16*)(ws + (0ull));
  float2*   ml     = (float2*)(ws + (16ull << 20));

  ra_convert_in<<<dim3(1024, 3), 256, 0, stream>>>(query, key_, value, Xq, Xk, Xv);
  ra_transpose_w<<<dim3(32, 32, 4), dim3(32, 8), 0, stream>>>(Wq, Wk, Wv, Wo, WqT, WkT, WvT, WoT);
  ra_proj_gemm<<<dim3(32, 8, 3), 256, 0, stream>>>(Xq, Xk, Xv, WqT, WkT, WvT, bq, bk, bv,
                                                   q_ws, k_ws, vT_ws);
  ra_attn<<<dim3(64, 4, 2), 512, 0, stream>>>(q_ws, k_ws, vT_ws, mask, rel, o_part, ml);
  ra_combine<<<2048, 256, 0, stream>>>(o_part, ml, x_ws);
  ra_out_gemm<<<dim3(32, 8), 256, 0, stream>>>(x_ws, WoT, bo, out);
}

// Round 5
// 372.492 us; speedup vs baseline: 1.7134x; 1.2520x over previous
//
#include <hip/hip_runtime.h>
#include <hip/hip_bf16.h>

// RelativeAttention: out = ((softmax(((QK^T)*s + Q.rel)*s with mask) V) Wo + bo
// B=4 S=1024 D=1024 H=16 dk=64.  All matmuls in bf16 MFMA (16x16x32), f32 accum.

typedef unsigned short u16;
typedef unsigned int u32;
typedef __attribute__((ext_vector_type(8))) short bf16x8;
typedef __attribute__((ext_vector_type(4))) float f32x4;

#define SB 1024
#define DM 1024
#define NHD 16
#define DKH 64
#define NBATCH 4

// pin point: loads above cannot sink below; loads below cannot hoist above
#define PIN() do { __builtin_amdgcn_sched_barrier(0); asm volatile("" ::: "memory"); } while (0)

__device__ __forceinline__ u16 f2bf(float x) {
  union { __hip_bfloat16 b; u16 u; } c;
  c.b = __float2bfloat16(x);
  return c.u;
}

__device__ __forceinline__ f32x4 mfma16(bf16x8 a, bf16x8 b, f32x4 c) {
  return __builtin_amdgcn_mfma_f32_16x16x32_bf16(a, b, c, 0, 0, 0);
}

__device__ __forceinline__ bf16x8 cvt8r(float4 v0, float4 v1) {
  bf16x8 r;
  r[0] = (short)f2bf(v0.x); r[1] = (short)f2bf(v0.y);
  r[2] = (short)f2bf(v0.z); r[3] = (short)f2bf(v0.w);
  r[4] = (short)f2bf(v1.x); r[5] = (short)f2bf(v1.y);
  r[6] = (short)f2bf(v1.z); r[7] = (short)f2bf(v1.w);
  return r;
}

// ---------------- f32 -> bf16 for the 3 input activations ----------------
__global__ void ra_convert_in(const float* __restrict__ q, const float* __restrict__ k,
                              const float* __restrict__ v,
                              u16* __restrict__ Xq, u16* __restrict__ Xk, u16* __restrict__ Xv)
{
  const int z = blockIdx.y;
  const float* src = (z == 0) ? q : (z == 1) ? k : v;
  u16* dst = (z == 0) ? Xq : (z == 1) ? Xk : Xv;
  const int n4 = NBATCH * SB * DM / 4;
  int idx = blockIdx.x * blockDim.x + threadIdx.x;
  int stride = gridDim.x * blockDim.x;
  for (int i = idx; i < n4; i += stride) {
    float4 v4 = *((const float4*)src + i);
    uint2 o;
    o.x = (u32)f2bf(v4.x) | ((u32)f2bf(v4.y) << 16);
    o.y = (u32)f2bf(v4.z) | ((u32)f2bf(v4.w) << 16);
    *((uint2*)dst + i) = o;
  }
}

// ---------------- W (f32 [k][n]) -> W^T (bf16 [n][k]) ----------------
__global__ void ra_transpose_w(const float* __restrict__ Wq, const float* __restrict__ Wk,
                               const float* __restrict__ Wv, const float* __restrict__ Wo,
                               u16* __restrict__ WqT, u16* __restrict__ WkT,
                               u16* __restrict__ WvT, u16* __restrict__ WoT)
{
  const int z = blockIdx.z;
  const float* W = (z == 0) ? Wq : (z == 1) ? Wk : (z == 2) ? Wv : Wo;
  u16* WT = (z == 0) ? WqT : (z == 1) ? WkT : (z == 2) ? WvT : WoT;
  __shared__ float tile[32][33];
  const int x0 = blockIdx.x * 32, y0 = blockIdx.y * 32;
  const int tx = threadIdx.x, ty = threadIdx.y;
#pragma unroll
  for (int yy = 0; yy < 4; ++yy) {
    int r = ty + yy * 8;
    tile[r][tx] = W[(size_t)(y0 + r) * DM + x0 + tx];
  }
  __syncthreads();
#pragma unroll
  for (int yy = 0; yy < 4; ++yy) {
    int r = ty + yy * 8;
    WT[(size_t)(x0 + r) * DM + y0 + tx] = f2bf(tile[tx][r]);
  }
}

// ---------------- shared 128x128x1024 bf16 GEMM core ----------------
__device__ __forceinline__ void gemm_core_128(const u16* __restrict__ A, const u16* __restrict__ Bt,
                                              int bm0, int bn0, u16* sh, f32x4 (&acc)[4][4])
{
  u16* As = sh;             // [128][72]
  u16* Bs = sh + 128 * 72;  // [128][72]
  const int tid = threadIdx.x;
  const int lane = tid & 63, wid = tid >> 6;
  const int l15 = lane & 15, l4 = lane >> 4;
  const int wr = (wid >> 1) * 64, wc = (wid & 1) * 64;
  for (int k0 = 0; k0 < DM; k0 += 64) {
#pragma unroll
    for (int it = 0; it < 4; ++it) {
      int c = tid + it * 256;
      int rw = c >> 3, kc = c & 7;
      *(uint4*)(As + rw * 72 + kc * 8) = *(const uint4*)(A + (size_t)(bm0 + rw) * DM + k0 + kc * 8);
      *(uint4*)(Bs + rw * 72 + kc * 8) = *(const uint4*)(Bt + (size_t)(bn0 + rw) * DM + k0 + kc * 8);
    }
    __syncthreads();
#pragma unroll
    for (int kf = 0; kf < 2; ++kf) {
      bf16x8 a[4], b[4];
#pragma unroll
      for (int mf = 0; mf < 4; ++mf)
        a[mf] = *(const bf16x8*)(As + (wr + mf * 16 + l15) * 72 + kf * 32 + l4 * 8);
#pragma unroll
      for (int nf = 0; nf < 4; ++nf)
        b[nf] = *(const bf16x8*)(Bs + (wc + nf * 16 + l15) * 72 + kf * 32 + l4 * 8);
#pragma unroll
      for (int mf = 0; mf < 4; ++mf)
#pragma unroll
        for (int nf = 0; nf < 4; ++nf)
          acc[mf][nf] = mfma16(a[mf], b[nf], acc[mf][nf]);
    }
    __syncthreads();
  }
}

// ---------------- projections: q/k -> [bh][s][dk], v -> [bh][dk][s] ----------------
__global__ __launch_bounds__(256, 2)
void ra_proj_gemm(const u16* __restrict__ Xq, const u16* __restrict__ Xk, const u16* __restrict__ Xv,
                  const u16* __restrict__ WqT, const u16* __restrict__ WkT, const u16* __restrict__ WvT,
                  const float* __restrict__ bq, const float* __restrict__ bk, const float* __restrict__ bv,
                  u16* __restrict__ q_ws, u16* __restrict__ k_ws, u16* __restrict__ vT_ws)
{
  __shared__ alignas(16) u16 sh[128 * 72 * 2];
  const int mode = blockIdx.z;
  const u16* A  = (mode == 0) ? Xq : (mode == 1) ? Xk : Xv;
  const u16* Bt = (mode == 0) ? WqT : (mode == 1) ? WkT : WvT;
  const float* bias = (mode == 0) ? bq : (mode == 1) ? bk : bv;
  const int bm0 = blockIdx.x * 128, bn0 = blockIdx.y * 128;
  f32x4 acc[4][4] = {};
  gemm_core_128(A, Bt, bm0, bn0, sh, acc);
  const int tid = threadIdx.x;
  const int lane = tid & 63, wid = tid >> 6;
  const int l15 = lane & 15, l4 = lane >> 4;
  const int wr = (wid >> 1) * 64, wc = (wid & 1) * 64;
  const int b_idx = bm0 >> 10;
  const int srow0 = bm0 & (SB - 1);
  if (mode < 2) {
    u16* outp = (mode == 0) ? q_ws : k_ws;
#pragma unroll
    for (int nf = 0; nf < 4; ++nf) {
      int nn = bn0 + wc + nf * 16 + l15;
      float bv_ = bias[nn];
      int h = nn >> 6, d = nn & 63;
#pragma unroll
      for (int mf = 0; mf < 4; ++mf)
#pragma unroll
        for (int r = 0; r < 4; ++r) {
          int m = wr + mf * 16 + l4 * 4 + r;
          outp[((size_t)(b_idx * NHD + h) * SB + srow0 + m) * DKH + d] = f2bf(acc[mf][nf][r] + bv_);
        }
    }
  } else {
    u16* ct = sh;  // [128][136]
#pragma unroll
    for (int nf = 0; nf < 4; ++nf) {
      int nl = wc + nf * 16 + l15;
      float bv_ = bias[bn0 + nl];
#pragma unroll
      for (int mf = 0; mf < 4; ++mf)
#pragma unroll
        for (int r = 0; r < 4; ++r) {
          int m = wr + mf * 16 + l4 * 4 + r;
          ct[nl * 136 + m] = f2bf(acc[mf][nf][r] + bv_);
        }
    }
    __syncthreads();
#pragma unroll
    for (int it = 0; it < 8; ++it) {
      int c = tid + it * 256;
      int n = c >> 4, mc2 = c & 15;
      uint4 v = *(const uint4*)(ct + n * 136 + mc2 * 8);
      int nn = bn0 + n;
      int h = nn >> 6, d = nn & 63;
      *(uint4*)(vT_ws + ((size_t)(b_idx * NHD + h) * DKH + d) * SB + srow0 + mc2 * 8) = v;
    }
  }
}

// ---------------- final projection: out = x @ Wo + bo (f32 out) ----------------
__global__ __launch_bounds__(256, 2)
void ra_out_gemm(const u16* __restrict__ X, const u16* __restrict__ WoT,
                 const float* __restrict__ bo, float* __restrict__ out)
{
  __shared__ alignas(16) u16 sh[128 * 72 * 2];
  const int bm0 = blockIdx.x * 128, bn0 = blockIdx.y * 128;
  f32x4 acc[4][4] = {};
  gemm_core_128(X, WoT, bm0, bn0, sh, acc);
  const int tid = threadIdx.x;
  const int lane = tid & 63, wid = tid >> 6;
  const int l15 = lane & 15, l4 = lane >> 4;
  const int wr = (wid >> 1) * 64, wc = (wid & 1) * 64;
#pragma unroll
  for (int nf = 0; nf < 4; ++nf) {
    int nn = bn0 + wc + nf * 16 + l15;
    float bv_ = bo[nn];
#pragma unroll
    for (int mf = 0; mf < 4; ++mf)
#pragma unroll
      for (int r = 0; r < 4; ++r) {
        int m = wr + mf * 16 + l4 * 4 + r;
        out[(size_t)(bm0 + m) * DM + nn] = acc[mf][nf][r] + bv_;
      }
  }
}

// ---------------- fused attention v5 ----------------
// 1 block/CU, 8 waves, 256-VGPR budget (launch_bounds(512,1)).  Block = (i-tile 16,
// batch g), j-tile 16, 64 iterations, ONE barrier per iteration.
//  - K/V tiles: global_load_lds, double-buffered (no VGPR cost). K source pre-XOR-
//    swizzled so s1 ds_read_b128 fragments are conflict-free.
//  - rel/mask: register prefetch, single set, reissued right after consumption.
//  - s1 = mfma(K,Q): lane l15 = i, regs = j.  p[4] stays in-lane and IS the PV
//    A-fragment (K=32 mfma, upper half zero) -> no p exchange at all.
//  - s2 = mfma(Q_bh, rel): exchanged via small fp16 LDS tile, double-buffered.
__global__ __launch_bounds__(512, 1)
void ra_attn(const u16* __restrict__ q_ws, const u16* __restrict__ k_ws,
             const u16* __restrict__ vT_ws, const int* __restrict__ mask,
             const float* __restrict__ rel, u16* __restrict__ x_ws)
{
  __shared__ alignas(16) u16 Kb[2][16384];        // [bh][j][d] 16x16x64 bf16, src-swizzled
  __shared__ alignas(16) u16 Vb[2][16416];        // [bh][d][j] 16x64x16 bf16 (+pad)
  __shared__ alignas(16) _Float16 s2t[2][5184];   // i*324 + j*20 + bh

  const int tid = threadIdx.x, wid = tid >> 6, lane = tid & 63;
  const int l15 = lane & 15, l4 = lane >> 4;
  const int g = blockIdx.y, i0 = blockIdx.x * 16, bh0 = g * NHD;
  const float scl1 = 0.125f, scl2 = 0.015625f;  // 1/sqrt(dk), 1/dk

  // ---- persistent q fragments ----
  bf16x8 q1[2][2];  // [bx][kf]: lane l15 = i-row   (B-frag of s1)
  bf16x8 q2[2][2];  // [ix][kf]: lane l15 = bh-row  (A-frag of s2)
#pragma unroll
  for (int bx = 0; bx < 2; ++bx) {
    const u16* qp = q_ws + ((size_t)(bh0 + wid * 2 + bx) * SB + i0 + l15) * DKH + l4 * 8;
    q1[bx][0] = *(const bf16x8*)qp;
    q1[bx][1] = *(const bf16x8*)(qp + 32);
  }
#pragma unroll
  for (int ix = 0; ix < 2; ++ix) {
    const u16* qp = q_ws + ((size_t)(bh0 + l15) * SB + i0 + wid * 2 + ix) * DKH + l4 * 8;
    q2[ix][0] = *(const bf16x8*)qp;
    q2[ix][1] = *(const bf16x8*)(qp + 32);
  }

  // ---- staging helpers (inline) ----
#define STAGE_K(JB, BUF)                                                                  \
  {                                                                                       \
    _Pragma("unroll") for (int n = 0; n < 4; ++n) {                                       \
      const int C = n * 512 + wid * 64 + lane;                                            \
      const int bh_ = C >> 7, j_ = (C >> 3) & 15, c_ = C & 7;                             \
      const u16* gp = k_ws + ((size_t)(bh0 + bh_) * SB + (JB) + j_) * DKH + (c_ ^ (j_ & 7)) * 8; \
      u16* lp = Kb[BUF] + (n * 512 + wid * 64) * 8;                                       \
      __builtin_amdgcn_global_load_lds((const __attribute__((address_space(1))) unsigned int*)gp, \
                                       (__attribute__((address_space(3))) unsigned int*)lp, 16, 0, 0); \
    }                                                                                     \
  }
#define STAGE_V(JB, BUF)                                                                  \
  {                                                                                       \
    _Pragma("unroll") for (int n = 0; n < 4; ++n) {                                       \
      const int C = n * 512 + wid * 64 + lane;                                            \
      const int bh_ = C >> 7, d_ = (C >> 1) & 63, h_ = C & 1;                             \
      const u16* gp = vT_ws + ((size_t)(bh0 + bh_) * DKH + d_) * SB + (JB) + h_ * 8;      \
      u16* lp = Vb[BUF] + (n * 512 + wid * 64) * 8;                                       \
      __builtin_amdgcn_global_load_lds((const __attribute__((address_space(1))) unsigned int*)gp, \
                                       (__attribute__((address_space(3))) unsigned int*)lp, 16, 0, 0); \
    }                                                                                     \
  }

  // ---- prologue: tile 0 ----
  float4 rr[2][4];
  int4 mr;
  STAGE_K(0, 0);
  STAGE_V(0, 0);
#pragma unroll
  for (int ix = 0; ix < 2; ++ix) {
    const float* rp = rel + ((size_t)(i0 + wid * 2 + ix) * SB + l15) * DKH + l4 * 8;
    rr[ix][0] = *(const float4*)rp;
    rr[ix][1] = *(const float4*)(rp + 4);
    rr[ix][2] = *(const float4*)(rp + 32);
    rr[ix][3] = *(const float4*)(rp + 36);
  }
  mr = *(const int4*)(mask + ((size_t)g * SB + i0 + l15) * SB + l4 * 4);
  PIN();
  __syncthreads();

  f32x4 acc_o[2][4] = {};
  float m_run[2] = {-1e30f, -1e30f}, l_run[2] = {0.f, 0.f};

  for (int jt = 0; jt < 64; ++jt) {
    const int jb = jt * 16;
    const int jbn = (jt < 63) ? jb + 16 : jb;
    const int cur = jt & 1, nxt = cur ^ 1;

    // [A] stage K(jt+1) -> other buffer (drains at this iter's barrier)
    STAGE_K(jbn, nxt);
    PIN();

    // [B] s1 = mfma(K, Q): lane l15 = i, regs = j (= l4*4 + r)
    f32x4 sc1[2];
#pragma unroll
    for (int bx = 0; bx < 2; ++bx) {
      f32x4 t = {};
#pragma unroll
      for (int kf = 0; kf < 2; ++kf) {
        bf16x8 ka = *(const bf16x8*)(Kb[cur] +
            ((((wid * 2 + bx) * 16 + l15) * 8 + ((kf * 4 + l4) ^ (l15 & 7))) * 8));
        t = mfma16(ka, q1[bx][kf], t);
      }
      sc1[bx] = t;
    }

    // [C] s2 = mfma(Q_bh, rel): lane l15 = j, regs = bh; write fp16 -> s2t[cur]
#pragma unroll
    for (int ix = 0; ix < 2; ++ix) {
      const int i2 = wid * 2 + ix;
      bf16x8 rb0 = cvt8r(rr[ix][0], rr[ix][1]);
      bf16x8 rb1 = cvt8r(rr[ix][2], rr[ix][3]);
      f32x4 t = {};
      t = mfma16(q2[ix][0], rb0, t);
      t = mfma16(q2[ix][1], rb1, t);
      union { _Float16 h[4]; uint2 u; } w;
#pragma unroll
      for (int r = 0; r < 4; ++r) w.h[r] = (_Float16)(t[r] * scl1);
      *(uint2*)&s2t[cur][i2 * 324 + l15 * 20 + l4 * 4] = w.u;
    }

    __syncthreads();  // the ONLY barrier: s2t visible, K/V(jt+1) staged & drained

    // [E] read s2 for own rows (i = l15), combine + softmax
    float s2f[2][4];
#pragma unroll
    for (int bx = 0; bx < 2; ++bx)
#pragma unroll
      for (int r = 0; r < 4; ++r)
        s2f[bx][r] = (float)s2t[cur][l15 * 324 + (l4 * 4 + r) * 20 + (wid * 2 + bx)];

    // [F] reissue rel(jt+1), stage V(jt+1) (covered until next iter's barrier/use)
#pragma unroll
    for (int ix = 0; ix < 2; ++ix) {
      const float* rp = rel + ((size_t)(i0 + wid * 2 + ix) * SB + jbn + l15) * DKH + l4 * 8;
      rr[ix][0] = *(const float4*)rp;
      rr[ix][1] = *(const float4*)(rp + 4);
      rr[ix][2] = *(const float4*)(rp + 32);
      rr[ix][3] = *(const float4*)(rp + 36);
    }
    STAGE_V(jbn, nxt);
    PIN();

    // softmax (per bx); p[4] stays in-lane as the PV A-fragment
    float fscs[2];
    bf16x8 pa[2];
#pragma unroll
    for (int bx = 0; bx < 2; ++bx) {
      float sv[4];
      sv[0] = (mr.x == 0) ? -1e9f : sc1[bx][0] * scl2 + s2f[bx][0];
      sv[1] = (mr.y == 0) ? -1e9f : sc1[bx][1] * scl2 + s2f[bx][1];
      sv[2] = (mr.z == 0) ? -1e9f : sc1[bx][2] * scl2 + s2f[bx][2];
      sv[3] = (mr.w == 0) ? -1e9f : sc1[bx][3] * scl2 + s2f[bx][3];
      float tmax = fmaxf(fmaxf(sv[0], sv[1]), fmaxf(sv[2], sv[3]));
      tmax = fmaxf(tmax, __shfl_xor(tmax, 16));
      tmax = fmaxf(tmax, __shfl_xor(tmax, 32));
      const float m_new = fmaxf(m_run[bx], tmax);
      const float fsc = __expf(m_run[bx] - m_new);
      float p0 = __expf(sv[0] - m_new), p1 = __expf(sv[1] - m_new);
      float p2 = __expf(sv[2] - m_new), p3 = __expf(sv[3] - m_new);
      float psum = p0 + p1 + p2 + p3;
      psum += __shfl_xor(psum, 16);
      psum += __shfl_xor(psum, 32);
      l_run[bx] = l_run[bx] * fsc + psum;
      m_run[bx] = m_new;
      fscs[bx] = fsc;
      union { bf16x8 v; u32 w[4]; } pk;
      pk.w[0] = (u32)f2bf(p0) | ((u32)f2bf(p1) << 16);
      pk.w[1] = (u32)f2bf(p2) | ((u32)f2bf(p3) << 16);
      pk.w[2] = 0; pk.w[3] = 0;
      pa[bx] = pk.v;
    }
    // reissue mask(jt+1) (just consumed)
    mr = *(const int4*)(mask + ((size_t)g * SB + i0 + l15) * SB + jbn + l4 * 4);
    PIN();

    // [H] PV: O = O*f + P.V  (V from LDS, b64 reads; regs m = i, lanes = d)
#pragma unroll
    for (int bx = 0; bx < 2; ++bx) {
      float f0 = __shfl(fscs[bx], l4 * 4 + 0);
      float f1 = __shfl(fscs[bx], l4 * 4 + 1);
      float f2 = __shfl(fscs[bx], l4 * 4 + 2);
      float f3 = __shfl(fscs[bx], l4 * 4 + 3);
#pragma unroll
      for (int df = 0; df < 4; ++df) {
        union { bf16x8 v; uint2 q[2]; } vb;
        vb.q[0] = *(const uint2*)(Vb[cur] +
                   (((wid * 2 + bx) * 64 + df * 16 + l15) * 16 + l4 * 4));
        vb.q[1] = make_uint2(0, 0);
        f32x4 c = acc_o[bx][df];
        c[0] *= f0; c[1] *= f1; c[2] *= f2; c[3] *= f3;
        acc_o[bx][df] = mfma16(pa[bx], vb.v, c);
      }
    }
  }

  // ---- epilogue: divide by softmax sum, write x[b][s][h*64+d] bf16 ----
#pragma unroll
  for (int bx = 0; bx < 2; ++bx) {
    float inv0 = 1.f / __shfl(l_run[bx], l4 * 4 + 0);
    float inv1 = 1.f / __shfl(l_run[bx], l4 * 4 + 1);
    float inv2 = 1.f / __shfl(l_run[bx], l4 * 4 + 2);
    float inv3 = 1.f / __shfl(l_run[bx], l4 * 4 + 3);
    const int col0 = (wid * 2 + bx) * DKH;
#pragma unroll
    for (int df = 0; df < 4; ++df) {
      const int col = col0 + df * 16 + l15;
      x_ws[((size_t)g * SB + i0 + l4 * 4 + 0) * DM + col] = f2bf(acc_o[bx][df][0] * inv0);
      x_ws[((size_t)g * SB + i0 + l4 * 4 + 1) * DM + col] = f2bf(acc_o[bx][df][1] * inv1);
      x_ws[((size_t)g * SB + i0 + l4 * 4 + 2) * DM + col] = f2bf(acc_o[bx][df][2] * inv2);
      x_ws[((size_t)g * SB + i0 + l4 * 4 + 3) * DM + col] = f2bf(acc_o[bx][df][3] * inv3);
    }
  }
#undef STAGE_K
#undef STAGE_V
}

// ---------------- launch ----------------
extern "C" void kernel_launch(void* const* d_in, const int* in_sizes, int n_in,
                              void* d_out, int out_size, void* d_ws, size_t ws_size,
                              hipStream_t stream) {
  const float* query = (const float*)d_in[0];
  const float* key_  = (const float*)d_in[1];
  const float* value = (const float*)d_in[2];
  const int*   mask  = (const int*)d_in[3];
  const float* rel   = (const float*)d_in[4];
  const float* Wq = (const float*)d_in[5];
  const float* Wk = (const float*)d_in[6];
  const float* Wv = (const float*)d_in[7];
  const float* Wo = (const float*)d_in[8];
  const float* bq = (const float*)d_in[9];
  const float* bk = (const float*)d_in[10];
  const float* bv = (const float*)d_in[11];
  const float* bo = (const float*)d_in[12];
  float* out = (float*)d_out;
  char* ws = (char*)d_ws;

  u16* Xq   = (u16*)(ws + (0ull));
  u16* Xk   = (u16*)(ws + (8ull << 20));
  u16* Xv   = (u16*)(ws + (16ull << 20));
  u16* WqT  = (u16*)(ws + (24ull << 20));
  u16* WkT  = (u16*)(ws + (26ull << 20));
  u16* WvT  = (u16*)(ws + (28ull << 20));
  u16* WoT  = (u16*)(ws + (30ull << 20));
  u16* q_ws = (u16*)(ws + (32ull << 20));
  u16* k_ws = (u16*)(ws + (40ull << 20));
  u16* vT_ws= (u16*)(ws + (48ull << 20));
  u16* x_ws = (u16*)(ws + (56ull << 20));

  ra_convert_in<<<dim3(1024, 3), 256, 0, stream>>>(query, key_, value, Xq, Xk, Xv);
  ra_transpose_w<<<dim3(32, 32, 4), dim3(32, 8), 0, stream>>>(Wq, Wk, Wv, Wo, WqT, WkT, WvT, WoT);
  ra_proj_gemm<<<dim3(32, 8, 3), 256, 0, stream>>>(Xq, Xk, Xv, WqT, WkT, WvT, bq, bk, bv,
                                                   q_ws, k_ws, vT_ws);
  ra_attn<<<dim3(64, 4), 512, 0, stream>>>(q_ws, k_ws, vT_ws, mask, rel, x_ws);
  ra_out_gemm<<<dim3(32, 8), 256, 0, stream>>>(x_ws, WoT, bo, out);
}